// Round 4
// baseline (6376.744 us; speedup 1.0000x reference)
//
#include <hip/hip_runtime.h>
#include <hip/hip_bf16.h>

typedef __hip_bfloat16 bf16;

#define NN 4096
#define DD 512
#define HH 4
#define DH 64
#define INNER 256
#define MM 256
#define LL 16
#define ROWS 32768

__device__ __forceinline__ float b2f(bf16 x) { return __bfloat162float(x); }

// adaptive input load / output store (f==1 -> float32, f==0 -> bf16)
__device__ __forceinline__ float ldf(const void* p, size_t i, int f) {
  return f ? ((const float*)p)[i] : __bfloat162float(((const bf16*)p)[i]);
}
__device__ __forceinline__ void stf(void* p, size_t i, float v, int f) {
  if (f) ((float*)p)[i] = v;
  else ((bf16*)p)[i] = __float2bfloat16(v);
}

// ---- 0. dtype detection: bf16-view of N(0,1) data has no huge exponents;
//         f32 misread as bf16 gives ~20% exponents >= 0xC8 ----
__global__ void detect_kernel(const void* x, int* flag) {
  __shared__ int red[256];
  int tid = threadIdx.x;
  const unsigned short* u = (const unsigned short*)x;
  int local = 0;
  for (int i = 0; i < 32; i++) {
    unsigned short e = (u[tid * 32 + i] >> 7) & 0xFF;
    if (e >= 0xC8) local++;
  }
  red[tid] = local; __syncthreads();
  #pragma unroll
  for (int s = 128; s > 0; s >>= 1) {
    if (tid < s) red[tid] += red[tid + s];
    __syncthreads();
  }
  if (tid == 0) *flag = (red[0] > 32) ? 1 : 0;
}

// ---- block reductions (blockDim.x == 256) ----
__device__ __forceinline__ float bred_max(float v, float* red) {
  int tid = threadIdx.x;
  red[tid] = v; __syncthreads();
  #pragma unroll
  for (int s = 128; s > 0; s >>= 1) {
    if (tid < s) red[tid] = fmaxf(red[tid], red[tid + s]);
    __syncthreads();
  }
  float r = red[0]; __syncthreads();
  return r;
}
__device__ __forceinline__ float bred_sum(float v, float* red) {
  int tid = threadIdx.x;
  red[tid] = v; __syncthreads();
  #pragma unroll
  for (int s = 128; s > 0; s >>= 1) {
    if (tid < s) red[tid] += red[tid + s];
    __syncthreads();
  }
  float r = red[0]; __syncthreads();
  return r;
}

// ---- 1. LayerNorm stats: (mean, rstd) per row ----
__global__ void ln_stats_kernel(const void* __restrict__ x, float* __restrict__ stats,
                                const int* dflag) {
  __shared__ float red[256];
  int f = *dflag;
  int row = blockIdx.x;
  int tid = threadIdx.x;
  size_t base = (size_t)row * DD;
  float v0 = ldf(x, base + tid, f);
  float v1 = ldf(x, base + tid + 256, f);
  float mean = bred_sum(v0 + v1, red) * (1.0f / DD);
  float d0 = v0 - mean, d1 = v1 - mean;
  float var = bred_sum(d0 * d0 + d1 * d1, red) * (1.0f / DD);
  if (tid == 0) {
    stats[row * 2]     = mean;
    stats[row * 2 + 1] = rsqrtf(var + 1e-5f);
  }
}

// ---- 2. QKV GEMM with fused LayerNorm on A-load; outputs bf16 q,k,v [B,h,N,dh] ----
__global__ void qkv_gemm(const void* __restrict__ x, const float* __restrict__ stats,
                         const void* __restrict__ g, const void* __restrict__ bb,
                         const void* __restrict__ Bw,
                         bf16* __restrict__ q, bf16* __restrict__ k, bf16* __restrict__ v,
                         const int* dflag) {
  __shared__ float As[32][17];
  __shared__ float Bs[16][33];
  int f = *dflag;
  int tx = threadIdx.x, ty = threadIdx.y;
  int lid = ty * 16 + tx;
  int row0 = blockIdx.x * 32;
  int col0 = blockIdx.y * 32;
  int ar = lid >> 4, ac = lid & 15;
  int br = lid >> 5, bc = lid & 31;
  float acc00 = 0, acc01 = 0, acc10 = 0, acc11 = 0;
  for (int k0 = 0; k0 < 512; k0 += 16) {
    int c = k0 + ac;
    float gc = ldf(g, c, f), bc_ = ldf(bb, c, f);
    {
      int r = row0 + ar;
      float mu = stats[r * 2], rs = stats[r * 2 + 1];
      As[ar][ac] = (ldf(x, (size_t)r * DD + c, f) - mu) * rs * gc + bc_;
    }
    {
      int r = row0 + ar + 16;
      float mu = stats[r * 2], rs = stats[r * 2 + 1];
      As[ar + 16][ac] = (ldf(x, (size_t)r * DD + c, f) - mu) * rs * gc + bc_;
    }
    Bs[br][bc]     = ldf(Bw, (size_t)(k0 + br) * 768 + col0 + bc, f);
    Bs[br + 8][bc] = ldf(Bw, (size_t)(k0 + br + 8) * 768 + col0 + bc, f);
    __syncthreads();
    #pragma unroll
    for (int kk = 0; kk < 16; kk++) {
      float a0 = As[ty][kk], a1 = As[ty + 16][kk];
      float b0 = Bs[kk][tx], b1 = Bs[kk][tx + 16];
      acc00 += a0 * b0; acc01 += a0 * b1; acc10 += a1 * b0; acc11 += a1 * b1;
    }
    __syncthreads();
  }
  float accs[2][2] = {{acc00, acc01}, {acc10, acc11}};
  #pragma unroll
  for (int i = 0; i < 2; i++) {
    #pragma unroll
    for (int j = 0; j < 2; j++) {
      int row = row0 + ty + i * 16;
      int c   = col0 + tx + j * 16;
      int which = c >> 8; int within = c & 255; int h = within >> 6; int d = within & 63;
      int b_ = row >> 12; int n = row & 4095;
      size_t idx = ((size_t)(b_ * HH + h) * NN + n) * DH + d;
      float val = accs[i][j];
      if (which == 0) q[idx] = __float2bfloat16(val * 0.125f);  // dh^-0.5
      else if (which == 1) k[idx] = __float2bfloat16(val);
      else v[idx] = __float2bfloat16(val);
    }
  }
}

// ---- 3. landmark means over groups of 16 (bf16 src -> f32 dst) ----
__global__ void landmark_kernel(const bf16* __restrict__ src, float* __restrict__ dst) {
  int idx = blockIdx.x * 256 + threadIdx.x;  // 524288 total
  int d = idx & 63;
  int j = (idx >> 6) & 255;
  int bh = idx >> 14;
  const bf16* s = src + ((size_t)bh * NN + j * LL) * DH + d;
  float acc = 0;
  #pragma unroll
  for (int i = 0; i < LL; i++) acc += b2f(s[i * DH]);
  dst[idx] = acc * (1.0f / LL);
}

// ---- 4. sim2 + softmax -> a2 [bh,256,256] ----
__global__ void a2_kernel(const float* __restrict__ ql, const float* __restrict__ kl,
                          float* __restrict__ a2) {
  __shared__ float qs[64];
  __shared__ float red[256];
  int bh = blockIdx.x >> 8;
  int i = blockIdx.x & 255;
  int tid = threadIdx.x;
  if (tid < 64) qs[tid] = ql[((size_t)bh * MM + i) * DH + tid];
  __syncthreads();
  const float* kr = kl + ((size_t)bh * MM + tid) * DH;
  float s = 0;
  #pragma unroll
  for (int d = 0; d < 64; d++) s += qs[d] * kr[d];
  float mx = bred_max(s, red);
  float e = expf(s - mx);
  float sm = bred_sum(e, red);
  a2[((size_t)bh * MM + i) * MM + tid] = e / sm;
}

// ---- 5a. global max of row-sums / col-sums of |a2| ----
__global__ void a2_maxsum(const float* __restrict__ a2, float* __restrict__ gmax) {
  __shared__ float red[256];
  int tid = threadIdx.x;
  int id = blockIdx.x;
  if (id < 8192) {
    int bh = id >> 8, i = id & 255;
    float s = fabsf(a2[((size_t)bh * MM + i) * MM + tid]);
    float tot = bred_sum(s, red);
    if (tid == 0) atomicMax((int*)gmax, __float_as_int(tot));
  } else {
    id -= 8192;
    int bh = id >> 8, j = id & 255;
    float s = fabsf(a2[((size_t)bh * MM + tid) * MM + j]);
    float tot = bred_sum(s, red);
    if (tid == 0) atomicMax((int*)gmax + 1, __float_as_int(tot));
  }
}

// ---- 5b. z0 = a2^T / (max_rowsum * max_colsum) ----
__global__ void zinit_kernel(const float* __restrict__ a2, const float* __restrict__ gmax,
                             float* __restrict__ z) {
  int idx = blockIdx.x * 256 + threadIdx.x;
  int j = idx & 255, i = (idx >> 8) & 255, bh = idx >> 16;
  float scale = 1.0f / (gmax[0] * gmax[1]);
  z[idx] = a2[((size_t)bh * MM + j) * MM + i] * scale;
}

// ---- 6. batched tiled matmul: C = alpha*I + beta*(A@B_eff), B_eff = gbA*I + gbB*B ----
__global__ void bmm_kernel(const float* __restrict__ A, const float* __restrict__ B_,
                           float* __restrict__ C, int Nn, int Kk,
                           long sA, long sB, long sC,
                           float alpha, float beta, float gbA, float gbB) {
  __shared__ float As[32][17];
  __shared__ float Bs[16][33];
  int bh = blockIdx.x;
  const float* Ab = A + (size_t)bh * sA;
  const float* Bb = B_ + (size_t)bh * sB;
  float* Cb = C + (size_t)bh * sC;
  int tx = threadIdx.x, ty = threadIdx.y;
  int lid = ty * 16 + tx;
  int row0 = blockIdx.y * 32, col0 = blockIdx.z * 32;
  int ar = lid >> 4, ac = lid & 15;
  int br = lid >> 5, bc = lid & 31;
  float acc00 = 0, acc01 = 0, acc10 = 0, acc11 = 0;
  for (int k0 = 0; k0 < Kk; k0 += 16) {
    As[ar][ac]      = Ab[(size_t)(row0 + ar) * Kk + k0 + ac];
    As[ar + 16][ac] = Ab[(size_t)(row0 + ar + 16) * Kk + k0 + ac];
    Bs[br][bc]     = gbA * ((k0 + br) == (col0 + bc))     + gbB * Bb[(size_t)(k0 + br) * Nn + col0 + bc];
    Bs[br + 8][bc] = gbA * ((k0 + br + 8) == (col0 + bc)) + gbB * Bb[(size_t)(k0 + br + 8) * Nn + col0 + bc];
    __syncthreads();
    #pragma unroll
    for (int kk = 0; kk < 16; kk++) {
      float a0 = As[ty][kk], a1 = As[ty + 16][kk];
      float b0 = Bs[kk][tx], b1 = Bs[kk][tx + 16];
      acc00 += a0 * b0; acc01 += a0 * b1; acc10 += a1 * b0; acc11 += a1 * b1;
    }
    __syncthreads();
  }
  int r0 = row0 + ty, r1 = row0 + ty + 16, c0 = col0 + tx, c1 = col0 + tx + 16;
  Cb[(size_t)r0 * Nn + c0] = alpha * (r0 == c0) + beta * acc00;
  Cb[(size_t)r0 * Nn + c1] = alpha * (r0 == c1) + beta * acc01;
  Cb[(size_t)r1 * Nn + c0] = alpha * (r1 == c0) + beta * acc10;
  Cb[(size_t)r1 * Nn + c1] = alpha * (r1 == c1) + beta * acc11;
}

// ---- 7. fused softmax(sim3) @ v -> a3v [bh,256,64] ----
__global__ void a3v_kernel(const float* __restrict__ ql, const bf16* __restrict__ kmat,
                           const bf16* __restrict__ vmat, float* __restrict__ a3v) {
  __shared__ float qs[64];
  __shared__ float sc[4096];
  __shared__ float red[256];
  __shared__ float part[256];
  int bh = blockIdx.x >> 8;
  int i = blockIdx.x & 255;
  int tid = threadIdx.x;
  if (tid < 64) qs[tid] = ql[((size_t)bh * MM + i) * DH + tid];
  __syncthreads();
  const bf16* kb = kmat + (size_t)bh * NN * DH;
  float lmax = -1e30f;
  for (int c = 0; c < 16; c++) {
    int n = c * 256 + tid;
    const bf16* kr = kb + (size_t)n * DH;
    float s = 0;
    #pragma unroll
    for (int d = 0; d < 64; d++) s += qs[d] * b2f(kr[d]);
    sc[n] = s;
    lmax = fmaxf(lmax, s);
  }
  float mx = bred_max(lmax, red);
  float lsum = 0;
  for (int c = 0; c < 16; c++) {
    int n = c * 256 + tid;
    float e = expf(sc[n] - mx);
    sc[n] = e;
    lsum += e;
  }
  float S = bred_sum(lsum, red);
  int d = tid & 63, ch = tid >> 6;
  const bf16* vb = vmat + (size_t)bh * NN * DH;
  float acc = 0;
  for (int n = ch * 1024; n < ch * 1024 + 1024; n++) acc += sc[n] * b2f(vb[(size_t)n * DH + d]);
  part[tid] = acc;
  __syncthreads();
  if (tid < 64) {
    float r = part[tid] + part[tid + 64] + part[tid + 128] + part[tid + 192];
    a3v[((size_t)bh * MM + i) * DH + tid] = r / S;
  }
}

// ---- 8. fused softmax(sim1) @ Wm + depthwise conv -> y bf16 chunk [4,4096,256] ----
__global__ void a1_kernel(const bf16* __restrict__ qmat, const float* __restrict__ kl,
                          const float* __restrict__ Wm, const bf16* __restrict__ vmat,
                          const void* __restrict__ wres, bf16* __restrict__ y,
                          const int* dflag, int bh0) {
  __shared__ float qs[64];
  __shared__ float p[256];
  __shared__ float red[256];
  __shared__ float part[256];
  int f = *dflag;
  int bh_local = blockIdx.x >> 12;   // [0,16)
  int bh = bh0 + bh_local;
  int n = blockIdx.x & 4095;
  int tid = threadIdx.x;
  if (tid < 64) qs[tid] = b2f(qmat[((size_t)bh * NN + n) * DH + tid]);
  __syncthreads();
  const float* kr = kl + ((size_t)bh * MM + tid) * DH;
  float s = 0;
  #pragma unroll
  for (int d2 = 0; d2 < 64; d2++) s += qs[d2] * kr[d2];
  float mx = bred_max(s, red);
  float e = expf(s - mx);
  float S = bred_sum(e, red);
  p[tid] = e / S;
  __syncthreads();
  int d = tid & 63, ch = tid >> 6;
  const float* Wb = Wm + (size_t)bh * MM * DH;
  float acc = 0;
  for (int j = ch * 64; j < ch * 64 + 64; j++) acc += p[j] * Wb[(size_t)j * DH + d];
  part[tid] = acc;
  __syncthreads();
  if (tid < 64) {
    float r = part[tid] + part[tid + 64] + part[tid + 128] + part[tid + 192];
    int h = bh & 3;
    const bf16* vb = vmat + (size_t)bh * NN * DH;
    float cv = 0;
    for (int kk = 0; kk < 33; kk++) {
      int nn = n + kk - 16;
      if (nn >= 0 && nn < NN) cv += ldf(wres, h * 33 + kk, f) * b2f(vb[(size_t)nn * DH + tid]);
    }
    int b_local = bh_local >> 2;
    y[((size_t)b_local * NN + n) * INNER + h * DH + tid] = __float2bfloat16(r + cv);
  }
}

// ---- 9. out GEMM chunk [16384,256]@[256,512] + b_out + x residual ----
__global__ void out_gemm(const bf16* __restrict__ A, const void* __restrict__ Bw,
                         const void* __restrict__ bo, const void* __restrict__ x,
                         void* __restrict__ out, const int* dflag, int rbase) {
  __shared__ float As[32][17];
  __shared__ float Bs[16][33];
  int f = *dflag;
  int tx = threadIdx.x, ty = threadIdx.y;
  int lid = ty * 16 + tx;
  int row0 = rbase + blockIdx.x * 32;   // global row
  int col0 = blockIdx.y * 32;
  int ar = lid >> 4, ac = lid & 15;
  int br = lid >> 5, bc = lid & 31;
  float acc00 = 0, acc01 = 0, acc10 = 0, acc11 = 0;
  for (int k0 = 0; k0 < 256; k0 += 16) {
    As[ar][ac]      = b2f(A[(size_t)(row0 - rbase + ar) * 256 + k0 + ac]);
    As[ar + 16][ac] = b2f(A[(size_t)(row0 - rbase + ar + 16) * 256 + k0 + ac]);
    Bs[br][bc]      = ldf(Bw, (size_t)(k0 + br) * 512 + col0 + bc, f);
    Bs[br + 8][bc]  = ldf(Bw, (size_t)(k0 + br + 8) * 512 + col0 + bc, f);
    __syncthreads();
    #pragma unroll
    for (int kk = 0; kk < 16; kk++) {
      float a0 = As[ty][kk], a1 = As[ty + 16][kk];
      float b0 = Bs[kk][tx], b1 = Bs[kk][tx + 16];
      acc00 += a0 * b0; acc01 += a0 * b1; acc10 += a1 * b0; acc11 += a1 * b1;
    }
    __syncthreads();
  }
  float accs[2][2] = {{acc00, acc01}, {acc10, acc11}};
  #pragma unroll
  for (int i = 0; i < 2; i++) {
    #pragma unroll
    for (int j = 0; j < 2; j++) {
      int row = row0 + ty + i * 16;
      int c   = col0 + tx + j * 16;
      float val = accs[i][j] + ldf(bo, c, f) + ldf(x, (size_t)row * 512 + c, f);
      stf(out, (size_t)row * 512 + c, val, f);
    }
  }
}

extern "C" void kernel_launch(void* const* d_in, const int* in_sizes, int n_in,
                              void* d_out, int out_size, void* d_ws, size_t ws_size,
                              hipStream_t stream) {
  const void* x     = d_in[0];
  const void* ln_g  = d_in[1];
  const void* ln_b  = d_in[2];
  const void* w_qkv = d_in[3];
  const void* w_out = d_in[4];
  const void* b_out = d_in[5];
  const void* w_res = d_in[6];

  // ---- workspace (~65 MiB), small/critical buffers first ----
  float* ws    = (float*)d_ws;
  float* gmax  = ws;                    // 2 floats
  int*   dflag = (int*)(ws + 8);        // 1 int
  float* stats = ws + 16;               // 65536
  float* ql    = stats + 65536;         // 524288
  float* kl    = ql + 524288;
  float* a3v   = kl + 524288;
  float* Wm    = a3v + 524288;
  float* a2    = Wm + 524288;           // 2097152 (8 MiB; later reused as y chunk)
  bf16*  q     = (bf16*)(a2 + 2097152); // 8388608 bf16 each (16 MiB)
  bf16*  k     = q + 8388608;
  bf16*  v     = k + 8388608;           // ends ~65 MiB

  // ---- pinv work buffers live in d_out (>= 32 MiB, dead before out_gemm) ----
  float* W0 = (float*)d_out;
  float* W1 = W0 + 2097152;
  float* W2 = W1 + 2097152;
  float* W3 = W2 + 2097152;

  detect_kernel<<<1, 256, 0, stream>>>(x, dflag);
  hipMemsetAsync(gmax, 0, 2 * sizeof(float), stream);

  ln_stats_kernel<<<ROWS, 256, 0, stream>>>(x, stats, dflag);
  qkv_gemm<<<dim3(1024, 24), dim3(16, 16), 0, stream>>>(x, stats, ln_g, ln_b, w_qkv, q, k, v, dflag);
  landmark_kernel<<<2048, 256, 0, stream>>>(q, ql);
  landmark_kernel<<<2048, 256, 0, stream>>>(k, kl);
  a2_kernel<<<8192, 256, 0, stream>>>(ql, kl, a2);
  a2_maxsum<<<16384, 256, 0, stream>>>(a2, gmax);
  zinit_kernel<<<8192, 256, 0, stream>>>(a2, gmax, W0);

  // pinv: z' = 0.25 z (13I - xz(15I - xz(7I - xz))),  xz = a2 @ z
  float* zi = W0; float* f1 = W1; float* f2 = W2; float* f3 = W3;
  for (int it = 0; it < 6; it++) {
    bmm_kernel<<<dim3(32, 8, 8), dim3(16, 16), 0, stream>>>(a2, zi, f1, 256, 256, 65536, 65536, 65536, 0.f, 1.f, 0.f, 1.f);
    bmm_kernel<<<dim3(32, 8, 8), dim3(16, 16), 0, stream>>>(f1, f1, f2, 256, 256, 65536, 65536, 65536, 15.f, -1.f, 7.f, -1.f);
    bmm_kernel<<<dim3(32, 8, 8), dim3(16, 16), 0, stream>>>(f1, f2, f3, 256, 256, 65536, 65536, 65536, 13.f, -1.f, 0.f, 1.f);
    bmm_kernel<<<dim3(32, 8, 8), dim3(16, 16), 0, stream>>>(zi, f3, f2, 256, 256, 65536, 65536, 65536, 0.f, 0.25f, 0.f, 1.f);
    float* nzi = f2; f2 = f1; f1 = zi; zi = nzi;
  }
  // after 6 iters rotation lands zi == W0

  a3v_kernel<<<8192, 256, 0, stream>>>(ql, k, v, a3v);
  // Wm = a2inv @ a3v   [256,256]@[256,64]
  bmm_kernel<<<dim3(32, 8, 2), dim3(16, 16), 0, stream>>>(zi, a3v, Wm, 64, 256, 65536, 16384, 16384, 0.f, 1.f, 0.f, 1.f);

  // two half-batch passes; y chunk (4*4096*256 bf16 = 8 MiB) reuses dead a2 region
  bf16* y = (bf16*)a2;
  for (int c = 0; c < 2; c++) {
    a1_kernel<<<65536, 256, 0, stream>>>(q, kl, Wm, v, w_res, y, dflag, c * 16);
    out_gemm<<<dim3(512, 16), dim3(16, 16), 0, stream>>>(y, w_out, b_out, x, d_out, dflag, c * 16384);
  }
}

// Round 7
// 1771.882 us; speedup vs baseline: 3.5989x; 3.5989x over previous
//
#include <hip/hip_runtime.h>
#include <hip/hip_bf16.h>
#include <string.h>

typedef __hip_bfloat16 bf16;
typedef __attribute__((ext_vector_type(8))) __bf16 bf16x8;
typedef __attribute__((ext_vector_type(4))) float f32x4;
typedef __attribute__((ext_vector_type(8))) unsigned short u16x8;

#define NN 4096
#define DD 512
#define MM 256
#define ROWS 32768

__device__ __forceinline__ float b2f(bf16 x) { return __bfloat162float(x); }
__device__ __forceinline__ float u2f(unsigned short u) {
  return __uint_as_float(((unsigned int)u) << 16);
}
__device__ __forceinline__ unsigned short f2bu(float v) {
  bf16 h = __float2bfloat16(v);
  return *reinterpret_cast<unsigned short*>(&h);
}
// adaptive input load / output store (f==1 -> float32, f==0 -> bf16)
__device__ __forceinline__ float ldf(const void* p, size_t i, int f) {
  return f ? ((const float*)p)[i] : __bfloat162float(((const bf16*)p)[i]);
}
__device__ __forceinline__ void stf(void* p, size_t i, float v, int f) {
  if (f) ((float*)p)[i] = v;
  else ((bf16*)p)[i] = __float2bfloat16(v);
}

// ---- dtype detection ----
__global__ void detect_kernel(const void* x, int* flag) {
  __shared__ int red[256];
  int tid = threadIdx.x;
  const unsigned short* u = (const unsigned short*)x;
  int local = 0;
  for (int i = 0; i < 32; i++) {
    unsigned short e = (u[tid * 32 + i] >> 7) & 0xFF;
    if (e >= 0xC8) local++;
  }
  red[tid] = local; __syncthreads();
  #pragma unroll
  for (int s = 128; s > 0; s >>= 1) {
    if (tid < s) red[tid] += red[tid + s];
    __syncthreads();
  }
  if (tid == 0) *flag = (red[0] > 32) ? 1 : 0;
}

// ---- block reductions ----
__device__ __forceinline__ float bred_max(float v, float* red) {
  int tid = threadIdx.x;
  red[tid] = v; __syncthreads();
  #pragma unroll
  for (int s = 128; s > 0; s >>= 1) {
    if (tid < s) red[tid] = fmaxf(red[tid], red[tid + s]);
    __syncthreads();
  }
  float r = red[0]; __syncthreads();
  return r;
}
__device__ __forceinline__ float bred_sum(float v, float* red) {
  int tid = threadIdx.x;
  red[tid] = v; __syncthreads();
  #pragma unroll
  for (int s = 128; s > 0; s >>= 1) {
    if (tid < s) red[tid] += red[tid + s];
    __syncthreads();
  }
  float r = red[0]; __syncthreads();
  return r;
}

// ---- LayerNorm stats ----
__global__ void ln_stats_kernel(const void* __restrict__ x, float* __restrict__ stats,
                                const int* dflag) {
  __shared__ float red[256];
  int f = *dflag;
  int row = blockIdx.x, tid = threadIdx.x;
  size_t base = (size_t)row * DD;
  float v0 = ldf(x, base + tid, f);
  float v1 = ldf(x, base + tid + 256, f);
  float mean = bred_sum(v0 + v1, red) * (1.0f / DD);
  float d0 = v0 - mean, d1 = v1 - mean;
  float var = bred_sum(d0 * d0 + d1 * d1, red) * (1.0f / DD);
  if (tid == 0) {
    stats[row * 2] = mean;
    stats[row * 2 + 1] = rsqrtf(var + 1e-5f);
  }
}

// ---- generic transpose -> bf16 out: out[b][c][r] = in[b][r][c] ----
__global__ void transpose_kernel(const void* __restrict__ in, bf16* __restrict__ out,
                                 int R, int Cc, long sIn, long sOut,
                                 const int* dflag, int ovr) {
  int f = (ovr >= 0) ? ovr : *dflag;
  size_t o = (size_t)blockIdx.x * 256 + threadIdx.x;
  size_t per = (size_t)R * Cc;
  size_t b = o / per, rem = o % per;
  size_t c = rem / R, r = rem % R;
  out[b * sOut + c * (size_t)R + r] = __float2bfloat16(ldf(in, b * sIn + r * (size_t)Cc + c, f));
}

// ---- QKV GEMM: MFMA, LN fused on A-stage, scatter epilogue ----
__global__ __launch_bounds__(256) void gemm_qkv(
    const void* __restrict__ x, const float* __restrict__ stats,
    const void* __restrict__ g, const void* __restrict__ bb,
    const bf16* __restrict__ wT,  // [768][512]
    bf16* __restrict__ q, bf16* __restrict__ k, bf16* __restrict__ v,
    const int* __restrict__ dflag) {
  __shared__ __align__(16) unsigned short As[128][40];
  __shared__ __align__(16) unsigned short Bs[128][40];
  int f = *dflag;
  int tid = threadIdx.x;
  int m0 = blockIdx.x * 128, n0 = blockIdx.y * 128;
  int sr = tid >> 1, sh = (tid & 1) * 16;
  int wave = tid >> 6, lane = tid & 63;
  int wm = (wave & 1) * 64, wn = (wave >> 1) * 64;
  int l15 = lane & 15, quad = lane >> 4;
  f32x4 acc[4][4] = {};
  for (int k0 = 0; k0 < 512; k0 += 32) {
    {
      int r = m0 + sr;
      float mu = stats[r * 2], rs = stats[r * 2 + 1];
      #pragma unroll
      for (int e = 0; e < 16; e++) {
        int c = k0 + sh + e;
        float xv = ldf(x, (size_t)r * DD + c, f);
        As[sr][sh + e] = f2bu((xv - mu) * rs * ldf(g, c, f) + ldf(bb, c, f));
      }
    }
    {
      const bf16* src = wT + (size_t)(n0 + sr) * 512 + k0 + sh;
      *(u16x8*)&Bs[sr][sh] = *(const u16x8*)src;
      *(u16x8*)&Bs[sr][sh + 8] = *(const u16x8*)(src + 8);
    }
    __syncthreads();
    bf16x8 af[4], bfr[4];
    #pragma unroll
    for (int i = 0; i < 4; i++) af[i] = *(const bf16x8*)&As[wm + i * 16 + l15][quad * 8];
    #pragma unroll
    for (int j = 0; j < 4; j++) bfr[j] = *(const bf16x8*)&Bs[wn + j * 16 + l15][quad * 8];
    #pragma unroll
    for (int i = 0; i < 4; i++)
      #pragma unroll
      for (int j = 0; j < 4; j++)
        acc[i][j] = __builtin_amdgcn_mfma_f32_16x16x32_bf16(af[i], bfr[j], acc[i][j], 0, 0, 0);
    __syncthreads();
  }
  #pragma unroll
  for (int i = 0; i < 4; i++)
    #pragma unroll
    for (int j = 0; j < 4; j++)
      #pragma unroll
      for (int reg = 0; reg < 4; reg++) {
        int row = m0 + wm + i * 16 + quad * 4 + reg;
        int c = n0 + wn + j * 16 + l15;
        int which = c >> 8, within = c & 255, h = within >> 6, d = within & 63;
        int b_ = row >> 12, n = row & 4095;
        size_t idx = ((size_t)(b_ * 4 + h) * NN + n) * 64 + d;
        float val = acc[i][j][reg];
        if (which == 0) q[idx] = __float2bfloat16(val * 0.125f);
        else if (which == 1) k[idx] = __float2bfloat16(val);
        else v[idx] = __float2bfloat16(val);
      }
}

// ---- generic batched MFMA GEMM: C = A[M x K] @ Bt[N x K]^T ----
// modes: 0=f32 store, 1=bf16 store, 2=f32 atomicAdd (split-K), 3=bias+residual+dtype store
__global__ __launch_bounds__(256) void gemm_bt(
    const bf16* __restrict__ A, long ldA, long sA,
    const bf16* __restrict__ Bt, long ldB, long sB,
    void* __restrict__ C, long ldC, long sC,
    int N, int kLen, int nTiles, int mode,
    const void* __restrict__ bias, const void* __restrict__ resid,
    const int* __restrict__ dflag) {
  __shared__ __align__(16) unsigned short As[128][40];
  __shared__ __align__(16) unsigned short Bs[128][40];
  int tid = threadIdx.x;
  int b = blockIdx.x;
  int m0 = blockIdx.y * 128;
  int nt = blockIdx.z % nTiles, ks = blockIdx.z / nTiles;
  int n0 = nt * 128;
  long k0b = (long)ks * kLen;
  const bf16* Ab = A + (size_t)b * sA;
  const bf16* Bb = Bt + (size_t)b * sB;
  int sr = tid >> 1, sh = (tid & 1) * 16;
  int wave = tid >> 6, lane = tid & 63;
  int wm = (wave & 1) * 64, wn = (wave >> 1) * 64;
  int l15 = lane & 15, quad = lane >> 4;
  f32x4 acc[4][4] = {};
  for (int kc = 0; kc < kLen; kc += 32) {
    long k0 = k0b + kc;
    {
      const bf16* src = Ab + (size_t)(m0 + sr) * ldA + k0 + sh;
      *(u16x8*)&As[sr][sh] = *(const u16x8*)src;
      *(u16x8*)&As[sr][sh + 8] = *(const u16x8*)(src + 8);
    }
    if (n0 + sr < N) {
      const bf16* src = Bb + (size_t)(n0 + sr) * ldB + k0 + sh;
      *(u16x8*)&Bs[sr][sh] = *(const u16x8*)src;
      *(u16x8*)&Bs[sr][sh + 8] = *(const u16x8*)(src + 8);
    } else {
      u16x8 z = {};
      *(u16x8*)&Bs[sr][sh] = z;
      *(u16x8*)&Bs[sr][sh + 8] = z;
    }
    __syncthreads();
    bf16x8 af[4], bfr[4];
    #pragma unroll
    for (int i = 0; i < 4; i++) af[i] = *(const bf16x8*)&As[wm + i * 16 + l15][quad * 8];
    #pragma unroll
    for (int j = 0; j < 4; j++) bfr[j] = *(const bf16x8*)&Bs[wn + j * 16 + l15][quad * 8];
    #pragma unroll
    for (int i = 0; i < 4; i++)
      #pragma unroll
      for (int j = 0; j < 4; j++)
        acc[i][j] = __builtin_amdgcn_mfma_f32_16x16x32_bf16(af[i], bfr[j], acc[i][j], 0, 0, 0);
    __syncthreads();
  }
  int f = (mode == 3) ? *dflag : 0;
  #pragma unroll
  for (int i = 0; i < 4; i++)
    #pragma unroll
    for (int j = 0; j < 4; j++)
      #pragma unroll
      for (int reg = 0; reg < 4; reg++) {
        int row = m0 + wm + i * 16 + quad * 4 + reg;
        int col = n0 + wn + j * 16 + l15;
        if (col < N) {
          float val = acc[i][j][reg];
          size_t off = (size_t)row * ldC + col;
          if (mode == 0) (((float*)C) + (size_t)b * sC)[off] = val;
          else if (mode == 1) (((bf16*)C) + (size_t)b * sC)[off] = __float2bfloat16(val);
          else if (mode == 2) atomicAdd(((float*)C) + (size_t)b * sC + off, val);
          else {
            val += ldf(bias, col, f) + ldf(resid, off, f);
            stf(C, off, val, f);
          }
        }
      }
}

// ---- landmark means: bf16 src -> f32 dst (for a2/pinv) AND bf16 dst (for MFMA) ----
__global__ void landmark_kernel(const bf16* __restrict__ src, float* __restrict__ dstf,
                                bf16* __restrict__ dstb) {
  int idx = blockIdx.x * 256 + threadIdx.x;  // 524288
  int d = idx & 63, j = (idx >> 6) & 255, bh = idx >> 14;
  const bf16* s = src + ((size_t)bh * NN + j * 16) * 64 + d;
  float a = 0;
  #pragma unroll
  for (int i = 0; i < 16; i++) a += b2f(s[i * 64]);
  a *= (1.0f / 16);
  dstf[idx] = a;
  dstb[idx] = __float2bfloat16(a);
}

// ---- a2 = softmax(ql @ kl^T) f32, f32 inputs (pinv-sensitive path) ----
__global__ void a2_kernel(const float* __restrict__ ql, const float* __restrict__ kl,
                          float* __restrict__ a2) {
  __shared__ float qs[64];
  __shared__ float red[256];
  int bh = blockIdx.x >> 8, i = blockIdx.x & 255, tid = threadIdx.x;
  if (tid < 64) qs[tid] = ql[((size_t)bh * MM + i) * 64 + tid];
  __syncthreads();
  const float* kr = kl + ((size_t)bh * MM + tid) * 64;
  float s = 0;
  #pragma unroll
  for (int d = 0; d < 64; d++) s += qs[d] * kr[d];
  float mx = bred_max(s, red);
  float e = __expf(s - mx);
  float sm = bred_sum(e, red);
  a2[((size_t)bh * MM + i) * MM + tid] = e / sm;
}

__global__ void a2_maxsum(const float* __restrict__ a2, float* __restrict__ gmax) {
  __shared__ float red[256];
  int tid = threadIdx.x, id = blockIdx.x;
  if (id < 8192) {
    int bh = id >> 8, i = id & 255;
    float tot = bred_sum(fabsf(a2[((size_t)bh * MM + i) * MM + tid]), red);
    if (tid == 0) atomicMax((int*)gmax, __float_as_int(tot));
  } else {
    id -= 8192;
    int bh = id >> 8, j = id & 255;
    float tot = bred_sum(fabsf(a2[((size_t)bh * MM + tid) * MM + j]), red);
    if (tid == 0) atomicMax((int*)gmax + 1, __float_as_int(tot));
  }
}

__global__ void zinit_kernel(const float* __restrict__ a2, const float* __restrict__ gmax,
                             float* __restrict__ z) {
  int idx = blockIdx.x * 256 + threadIdx.x;
  int j = idx & 255, i = (idx >> 8) & 255, bh = idx >> 16;
  float scale = 1.0f / (gmax[0] * gmax[1]);
  z[idx] = a2[((size_t)bh * MM + j) * MM + i] * scale;
}

// ---- fp32 batched 64x64-tile GEMM: C = alpha*I + beta*(A @ (gbA*I + gbB*B)) ----
// B-tile staging: 16 k-rows x 64 cols at col0 (rb=tid>>4, c4=(tid&15)*4).
// NOTE: round-6's "Nn-guard" indexing here was an LDS-OOB bug; do not reintroduce.
__global__ __launch_bounds__(256) void bmm64(
    const float* __restrict__ A, const float* __restrict__ B_,
    float* __restrict__ C,
    int Nn, int Kk, long sA, long sB, long sC,
    float alpha, float beta, float gbA, float gbB) {
  __shared__ __align__(16) float As[16][68];
  __shared__ __align__(16) float Bs[16][68];
  int bh = blockIdx.x;
  int row0 = blockIdx.y * 64, col0 = blockIdx.z * 64;
  const float* Ab = A + (size_t)bh * sA;
  const float* Bb = B_ + (size_t)bh * sB;
  int tid = threadIdx.x, tx = tid & 15, ty = tid >> 4;
  float c[4][4] = {};
  for (int k0 = 0; k0 < Kk; k0 += 16) {
    {
      int r = tid >> 2, k4 = (tid & 3) * 4;
      const float* src = Ab + (size_t)(row0 + r) * Kk + k0 + k4;
      float4 av = *(const float4*)src;
      As[k4 + 0][r] = av.x; As[k4 + 1][r] = av.y; As[k4 + 2][r] = av.z; As[k4 + 3][r] = av.w;
    }
    {
      int rb = tid >> 4, c4 = (tid & 15) * 4;
      const float* src = Bb + (size_t)(k0 + rb) * Nn + col0 + c4;
      float4 bv = *(const float4*)src;
      bv.x *= gbB; bv.y *= gbB; bv.z *= gbB; bv.w *= gbB;
      int kk = k0 + rb;
      if (kk == col0 + c4 + 0) bv.x += gbA;
      if (kk == col0 + c4 + 1) bv.y += gbA;
      if (kk == col0 + c4 + 2) bv.z += gbA;
      if (kk == col0 + c4 + 3) bv.w += gbA;
      *(float4*)&Bs[rb][c4] = bv;
    }
    __syncthreads();
    #pragma unroll
    for (int kk = 0; kk < 16; kk++) {
      float4 a = *(const float4*)&As[kk][ty * 4];
      float4 b = *(const float4*)&Bs[kk][tx * 4];
      float ar[4] = {a.x, a.y, a.z, a.w};
      float br[4] = {b.x, b.y, b.z, b.w};
      #pragma unroll
      for (int i = 0; i < 4; i++)
        #pragma unroll
        for (int j = 0; j < 4; j++) c[i][j] += ar[i] * br[j];
    }
    __syncthreads();
  }
  #pragma unroll
  for (int i = 0; i < 4; i++)
    #pragma unroll
    for (int j = 0; j < 4; j++) {
      int r = row0 + ty * 4 + i, cc = col0 + tx * 4 + j;
      C[(size_t)bh * sC + (size_t)r * Nn + cc] = alpha * (r == cc) + beta * c[i][j];
    }
}

// ---- softmax over rows of 4096 (bf16 in -> bf16 out) ----
__global__ void softmax3_kernel(const bf16* __restrict__ S, bf16* __restrict__ P) {
  __shared__ float red[256];
  int row = blockIdx.x, tid = threadIdx.x;
  const bf16* sr = S + (size_t)row * 4096 + tid * 16;
  u16x8 v0 = *(const u16x8*)sr;
  u16x8 v1 = *(const u16x8*)(sr + 8);
  float vals[16];
  #pragma unroll
  for (int e = 0; e < 8; e++) { vals[e] = u2f(v0[e]); vals[e + 8] = u2f(v1[e]); }
  float lm = -1e30f;
  #pragma unroll
  for (int e = 0; e < 16; e++) lm = fmaxf(lm, vals[e]);
  float mx = bred_max(lm, red);
  float ls = 0;
  #pragma unroll
  for (int e = 0; e < 16; e++) { vals[e] = __expf(vals[e] - mx); ls += vals[e]; }
  float inv = 1.0f / bred_sum(ls, red);
  bf16* pr = P + (size_t)row * 4096 + tid * 16;
  #pragma unroll
  for (int e = 0; e < 16; e++) pr[e] = __float2bfloat16(vals[e] * inv);
}

// ---- fused sim1 + softmax -> P1 f32 [4][4096][256] ----
__global__ __launch_bounds__(256) void attn1_kernel(
    const bf16* __restrict__ q, const bf16* __restrict__ klbf,
    float* __restrict__ P1, int bh0) {
  __shared__ __align__(16) unsigned short Qs[64][72];
  __shared__ __align__(16) unsigned short Ks[256][72];
  __shared__ float redm[4][64];
  __shared__ float reds[4][64];
  int tid = threadIdx.x;
  int bhl = blockIdx.y, bh = bh0 + bhl;
  int n0 = blockIdx.x * 64;
  const bf16* qb = q + ((size_t)bh * NN + n0) * 64;
  const bf16* kb = klbf + (size_t)bh * 16384;
  {
    int r = tid >> 2, s = (tid & 3) * 16;
    *(u16x8*)&Qs[r][s] = *(const u16x8*)(qb + (size_t)r * 64 + s);
    *(u16x8*)&Qs[r][s + 8] = *(const u16x8*)(qb + (size_t)r * 64 + s + 8);
  }
  {
    const bf16* src = kb + (size_t)tid * 64;
    #pragma unroll
    for (int s8 = 0; s8 < 8; s8++) *(u16x8*)&Ks[tid][s8 * 8] = *(const u16x8*)(src + s8 * 8);
  }
  __syncthreads();
  int wave = tid >> 6, lane = tid & 63, l15 = lane & 15, quad = lane >> 4;
  f32x4 acc[4][4] = {};
  #pragma unroll
  for (int kc = 0; kc < 64; kc += 32) {
    bf16x8 af[4], bfr[4];
    #pragma unroll
    for (int i = 0; i < 4; i++) af[i] = *(const bf16x8*)&Qs[i * 16 + l15][kc + quad * 8];
    #pragma unroll
    for (int j = 0; j < 4; j++) bfr[j] = *(const bf16x8*)&Ks[wave * 64 + j * 16 + l15][kc + quad * 8];
    #pragma unroll
    for (int i = 0; i < 4; i++)
      #pragma unroll
      for (int j = 0; j < 4; j++)
        acc[i][j] = __builtin_amdgcn_mfma_f32_16x16x32_bf16(af[i], bfr[j], acc[i][j], 0, 0, 0);
  }
  float lm[4][4], ls[4][4], rinv[4][4];
  #pragma unroll
  for (int i = 0; i < 4; i++)
    #pragma unroll
    for (int reg = 0; reg < 4; reg++) {
      float m = acc[i][0][reg];
      m = fmaxf(m, acc[i][1][reg]); m = fmaxf(m, acc[i][2][reg]); m = fmaxf(m, acc[i][3][reg]);
      lm[i][reg] = m;
    }
  #pragma unroll
  for (int off = 1; off < 16; off <<= 1)
    #pragma unroll
    for (int i = 0; i < 4; i++)
      #pragma unroll
      for (int reg = 0; reg < 4; reg++) lm[i][reg] = fmaxf(lm[i][reg], __shfl_xor(lm[i][reg], off));
  if (l15 == 0)
    #pragma unroll
    for (int i = 0; i < 4; i++)
      #pragma unroll
      for (int reg = 0; reg < 4; reg++) redm[wave][i * 16 + quad * 4 + reg] = lm[i][reg];
  __syncthreads();
  #pragma unroll
  for (int i = 0; i < 4; i++)
    #pragma unroll
    for (int reg = 0; reg < 4; reg++) {
      int r = i * 16 + quad * 4 + reg;
      rinv[i][reg] = fmaxf(fmaxf(redm[0][r], redm[1][r]), fmaxf(redm[2][r], redm[3][r]));
      ls[i][reg] = 0;
    }
  #pragma unroll
  for (int i = 0; i < 4; i++)
    #pragma unroll
    for (int j = 0; j < 4; j++)
      #pragma unroll
      for (int reg = 0; reg < 4; reg++) {
        float e = __expf(acc[i][j][reg] - rinv[i][reg]);
        acc[i][j][reg] = e;
        ls[i][reg] += e;
      }
  #pragma unroll
  for (int off = 1; off < 16; off <<= 1)
    #pragma unroll
    for (int i = 0; i < 4; i++)
      #pragma unroll
      for (int reg = 0; reg < 4; reg++) ls[i][reg] += __shfl_xor(ls[i][reg], off);
  if (l15 == 0)
    #pragma unroll
    for (int i = 0; i < 4; i++)
      #pragma unroll
      for (int reg = 0; reg < 4; reg++) reds[wave][i * 16 + quad * 4 + reg] = ls[i][reg];
  __syncthreads();
  #pragma unroll
  for (int i = 0; i < 4; i++)
    #pragma unroll
    for (int reg = 0; reg < 4; reg++) {
      int r = i * 16 + quad * 4 + reg;
      rinv[i][reg] = 1.0f / (reds[0][r] + reds[1][r] + reds[2][r] + reds[3][r]);
    }
  float* Pb = P1 + ((size_t)bhl * NN + n0) * 256;
  #pragma unroll
  for (int i = 0; i < 4; i++)
    #pragma unroll
    for (int j = 0; j < 4; j++)
      #pragma unroll
      for (int reg = 0; reg < 4; reg++) {
        int r = i * 16 + quad * 4 + reg;
        int col = wave * 64 + j * 16 + l15;
        Pb[(size_t)r * 256 + col] = acc[i][j][reg] * rinv[i][reg];
      }
}

// ---- depthwise conv (33) residual add: y = p1f32 + conv(v), 4-bh chunk ----
__global__ __launch_bounds__(256) void conv_add_kernel(
    const float* __restrict__ p1, const bf16* __restrict__ v,
    const void* __restrict__ wres, bf16* __restrict__ y, const int* __restrict__ dflag,
    int bh0) {
  __shared__ __align__(16) unsigned short Vs[96][64];
  int f = *dflag;
  int tid = threadIdx.x;
  int bhl = blockIdx.y, bh = bh0 + bhl;
  int n0 = blockIdx.x * 64;
  int h = bh & 3, b_ = bh >> 2;
  const bf16* vb = v + (size_t)bh * (NN * 64);
  for (int rr = tid; rr < 384; rr += 256) {
    int r = rr >> 2, s = (rr & 3) * 16;
    int n = n0 - 16 + r;
    if (n >= 0 && n < NN) {
      *(u16x8*)&Vs[r][s] = *(const u16x8*)(vb + (size_t)n * 64 + s);
      *(u16x8*)&Vs[r][s + 8] = *(const u16x8*)(vb + (size_t)n * 64 + s + 8);
    } else {
      u16x8 z = {};
      *(u16x8*)&Vs[r][s] = z; *(u16x8*)&Vs[r][s + 8] = z;
    }
  }
  float w33[33];
  #pragma unroll
  for (int kk = 0; kk < 33; kk++) w33[kk] = ldf(wres, h * 33 + kk, f);
  __syncthreads();
  int d = tid & 63, rb = tid >> 6;
  for (int ii = 0; ii < 16; ii++) {
    int nl = ii * 4 + rb;
    float cv = 0;
    #pragma unroll
    for (int kk = 0; kk < 33; kk++) cv += w33[kk] * u2f(Vs[nl + kk][d]);
    int n = n0 + nl;
    float pv = p1[((size_t)bhl * NN + n) * 64 + d];
    y[((size_t)b_ * NN + n) * 256 + h * 64 + d] = __float2bfloat16(pv + cv);
  }
}

extern "C" void kernel_launch(void* const* d_in, const int* in_sizes, int n_in,
                              void* d_out, int out_size, void* d_ws, size_t ws_size,
                              hipStream_t stream) {
  const void* x     = d_in[0];
  const void* ln_g  = d_in[1];
  const void* ln_b  = d_in[2];
  const void* w_qkv = d_in[3];
  const void* w_out = d_in[4];
  const void* b_out = d_in[5];
  const void* w_res = d_in[6];

  // ---- ws layout (~67.4 MiB; round-4 proved >= ~81 MiB available) ----
  float* ws    = (float*)d_ws;
  float* gmax  = ws;                                   // 2 f
  int*   dflag = (int*)(ws + 2);                       // 1 int
  float* stats = ws + 256;                             // 65536 f
  bf16*  woutT = (bf16*)(stats + 65536);               // 131072 bf16
  float* qlf   = (float*)(stats + 65536 + 65536);      // 524288 f
  float* klf   = qlf + 524288;                         // 524288 f
  bf16*  qlbf  = (bf16*)(klf + 524288);                // 524288 bf16
  bf16*  klbf  = qlbf + 524288;                        // 524288 bf16
  float* a3v   = (float*)(klbf + 524288);              // 524288 f
  float* Wm    = a3v + 524288;                         // 524288 f
  float* a2    = Wm + 524288;                          // 2097152 f (vT scratch alias)
  bf16*  q     = (bf16*)(a2 + 2097152);                // 8388608 bf16
  bf16*  k     = q + 8388608;                          // 8388608 bf16 (y alias)
  bf16*  v     = k + 8388608;                          // 8388608 bf16
  bf16*  y     = k;                                    // alias (k dead after sim3)
  bf16*  vTbuf = (bf16*)a2;                            // 4 MiB chunk scratch in a2 region

  // ---- d_out scratch (<= 32 MiB at all times) ----
  char* dob = (char*)d_out;
  bf16* wqkvT = (bf16*)dob;                            // phase A
  bf16* S3    = (bf16*)dob;                            // 16 MiB
  bf16* P3    = (bf16*)(dob + (16u << 20));            // 16 MiB
  float* W0   = (float*)dob;                           // pinv: 4 x 8 MiB
  float* W1   = (float*)(dob + (8u << 20));
  float* W2   = (float*)(dob + (16u << 20));
  float* W3   = (float*)(dob + (24u << 20));
  float* P1   = (float*)dob;                           // 16 MiB (4 bh chunk, f32)
  float* p1f  = (float*)(dob + (16u << 20));           // 4 MiB  (4 bh chunk, f32)

  detect_kernel<<<1, 256, 0, stream>>>(x, dflag);
  hipMemsetAsync(gmax, 0, 2 * sizeof(float), stream);
  ln_stats_kernel<<<ROWS, 256, 0, stream>>>(x, stats, dflag);

  // weight transposes
  transpose_kernel<<<1536, 256, 0, stream>>>(w_qkv, wqkvT, 512, 768, 0, 0, dflag, -1);
  transpose_kernel<<<512, 256, 0, stream>>>(w_out, woutT, 256, 512, 0, 0, dflag, -1);

  // QKV (LN fused)
  gemm_qkv<<<dim3(256, 6), 256, 0, stream>>>(x, stats, ln_g, ln_b, wqkvT, q, k, v, dflag);

  // landmarks (f32 + bf16)
  landmark_kernel<<<2048, 256, 0, stream>>>(q, qlf, qlbf);
  landmark_kernel<<<2048, 256, 0, stream>>>(k, klf, klbf);

  // sim3 -> softmax -> @v (4 chunks of 8 bh), a3v via split-K f32 atomics
  hipMemsetAsync(a3v, 0, 524288 * sizeof(float), stream);
  for (int c = 0; c < 4; c++) {
    transpose_kernel<<<8192, 256, 0, stream>>>(v + (size_t)c * 8 * 262144, vTbuf,
                                               4096, 64, 262144, 262144, dflag, 0);
    gemm_bt<<<dim3(8, 2, 32), 256, 0, stream>>>(
        qlbf + (size_t)c * 8 * 16384, 64, 16384,
        k + (size_t)c * 8 * 262144, 64, 262144,
        S3, 4096, 1048576, 4096, 64, 32, 1, nullptr, nullptr, dflag);
    softmax3_kernel<<<2048, 256, 0, stream>>>(S3, P3);
    gemm_bt<<<dim3(8, 2, 16), 256, 0, stream>>>(
        P3, 4096, 1048576, vTbuf, 4096, 262144,
        a3v + (size_t)c * 131072, 64, 16384, 64, 256, 1, 2, nullptr, nullptr, dflag);
  }

  // a2 path (f32 landmarks) + pinv in d_out
  a2_kernel<<<8192, 256, 0, stream>>>(qlf, klf, a2);
  a2_maxsum<<<16384, 256, 0, stream>>>(a2, gmax);
  zinit_kernel<<<8192, 256, 0, stream>>>(a2, gmax, W0);

  float* zi = W0; float* f1 = W1; float* f2 = W2; float* f3 = W3;
  for (int it = 0; it < 6; it++) {
    bmm64<<<dim3(32, 4, 4), 256, 0, stream>>>(a2, zi, f1, 256, 256, 65536, 65536, 65536, 0.f, 1.f, 0.f, 1.f);
    bmm64<<<dim3(32, 4, 4), 256, 0, stream>>>(f1, f1, f2, 256, 256, 65536, 65536, 65536, 15.f, -1.f, 7.f, -1.f);
    bmm64<<<dim3(32, 4, 4), 256, 0, stream>>>(f1, f2, f3, 256, 256, 65536, 65536, 65536, 13.f, -1.f, 0.f, 1.f);
    bmm64<<<dim3(32, 4, 4), 256, 0, stream>>>(zi, f3, f2, 256, 256, 65536, 65536, 65536, 0.f, 0.25f, 0.f, 1.f);
    float* nzi = f2; f2 = f1; f1 = zi; zi = nzi;
  }

  // Wm = z6 @ a3v -> f32 in ws (before d_out reuse)
  bmm64<<<dim3(32, 4, 1), 256, 0, stream>>>(zi, a3v, Wm, 64, 256, 65536, 16384, 16384, 0.f, 1.f, 0.f, 1.f);

  // a1 softmax (f32 P1) + f32 PV1 + conv residual, 8 chunks of 4 bh
  for (int c = 0; c < 8; c++) {
    attn1_kernel<<<dim3(64, 4), 256, 0, stream>>>(q, klbf, P1, c * 4);
    bmm64<<<dim3(4, 64, 1), 256, 0, stream>>>(
        P1, Wm + (size_t)c * 4 * 16384, p1f,
        64, 256, 1048576, 16384, 262144, 0.f, 1.f, 0.f, 1.f);
    conv_add_kernel<<<dim3(64, 4), 256, 0, stream>>>(p1f, v, w_res, y, dflag, c * 4);
  }

  // out = y @ w_out + b_out + x -> d_out (dtype-adaptive)
  gemm_bt<<<dim3(1, 256, 4), 256, 0, stream>>>(
      y, 256, 0, woutT, 256, 0,
      d_out, 512, 0, 512, 256, 4, 3, b_out, x, dflag);
}